// Round 10
// baseline (1295.116 us; speedup 1.0000x reference)
//
#include <hip/hip_runtime.h>
#include <hip/hip_bf16.h>

#define NN 100000
#define NE 3200000
#define NG 4096
#define NB 512          // blocks in hist/pairs; NE/NB = 6250 exactly
#define NBK 782         // coarse buckets of 128 nodes

typedef unsigned short ushort_t;
typedef short short8 __attribute__((ext_vector_type(8)));
typedef float floatx4 __attribute__((ext_vector_type(4)));

__device__ __forceinline__ float bf2f(unsigned short u){
  union{unsigned int i; float f;} x; x.i = ((unsigned)u)<<16; return x.f;
}
__device__ __forceinline__ ushort_t f2bf(float f){
  union{float f; unsigned int i;} x; x.f = f;
  unsigned int r = x.i + 0x7fff + ((x.i >> 16) & 1);
  return (ushort_t)(r >> 16);
}

// ---------------- CSR build: hierarchical counting sort ----------------

// also zeroes stats (65536 B) + tickets (16 B) at zbase
__global__ __launch_bounds__(512) void k_hist(const int* __restrict__ ei, int* __restrict__ histT,
                                              float4* __restrict__ zbase){
  __shared__ int lh[NBK];
  int b = blockIdx.x, t = threadIdx.x;
  int gtid = b*512 + t;
  if (gtid < 4098) zbase[gtid] = make_float4(0.f,0.f,0.f,0.f);
  for (int k=t; k<NBK; k+=512) lh[k]=0;
  __syncthreads();
  int e0 = b*(NE/NB);
  for (int e=e0+t; e<e0+(NE/NB); e+=512) atomicAdd(&lh[ei[NE+e]>>7], 1);
  __syncthreads();
  for (int k=t; k<NBK; k+=512) histT[(size_t)k*NB+b] = lh[k];
}

__global__ __launch_bounds__(256) void k_scanA(int* __restrict__ histT, int* __restrict__ total){
  int wv = blockIdx.x*4 + (threadIdx.x>>6);
  int lane = threadIdx.x & 63;
  if (wv >= NBK) return;
  int* row = histT + (size_t)wv*NB;
  int carry = 0;
  #pragma unroll
  for (int ch=0; ch<NB/64; ++ch){
    int a = row[ch*64+lane];
    int inc = a;
    for (int off=1; off<64; off<<=1){
      int x = __shfl_up(inc, off, 64);
      if (lane >= off) inc += x;
    }
    row[ch*64+lane] = carry + inc - a;       // exclusive
    carry += __shfl(inc, 63, 64);
  }
  if (lane==0) total[wv] = carry;
}

__global__ void k_scanB(const int* __restrict__ total, int* __restrict__ base){
  __shared__ int lds[1024];
  int t = threadIdx.x;
  int v = (t < NBK)? total[t] : 0;
  lds[t] = v; __syncthreads();
  for (int off=1; off<1024; off<<=1){
    int x = (t>=off)? lds[t-off] : 0;
    __syncthreads();
    lds[t] += x;
    __syncthreads();
  }
  if (t < NBK)      base[t]   = lds[t]-v;
  if (t == NBK-1)   base[NBK] = lds[t];      // == NE
}

__global__ __launch_bounds__(512) void k_pairs(const int* __restrict__ ei,
    const int* __restrict__ histT, const int* __restrict__ base,
    int* __restrict__ pairs){
  __shared__ int cur[NBK];
  int b = blockIdx.x, t = threadIdx.x;
  for (int k=t; k<NBK; k+=512) cur[k] = base[k] + histT[(size_t)k*NB + b];
  __syncthreads();
  int e0 = b*(NE/NB);
  for (int e=e0+t; e<e0+(NE/NB); e+=512){
    int src = ei[e], dst = ei[NE+e];
    int p = atomicAdd(&cur[dst>>7], 1);      // LDS atomic
    pairs[p] = (src << 7) | (dst & 127);
  }
}

// per-bucket 7-bit counting sort -> csr; colptr, dinv
__global__ __launch_bounds__(512) void k_fine(const int* __restrict__ pairs,
    const int* __restrict__ base, int* __restrict__ csr,
    int* __restrict__ colptr, float* __restrict__ dinv){
  __shared__ int cnt[128], off[128];
  int k = blockIdx.x, t = threadIdx.x;
  if (t < 128) cnt[t] = 0;
  __syncthreads();
  int s = base[k], e = base[k+1];
  for (int i=s+t; i<e; i+=512) atomicAdd(&cnt[pairs[i] & 127], 1);
  __syncthreads();
  int v = (t<128)? cnt[t] : 0;
  if (t<128) off[t] = v;
  __syncthreads();
  for (int o=1; o<128; o<<=1){
    int x = (t>=o && t<128)? off[t-o] : 0;
    __syncthreads();
    if (t<128) off[t] += x;
    __syncthreads();
  }
  int node0 = k*128;
  if (t < 128 && node0+t < NN){
    colptr[node0+t] = s + off[t] - v;
    dinv[node0+t]   = rsqrtf((float)cnt[t] + 1.0f);
  }
  if (k == NBK-1 && t == 0) colptr[NN] = NE;
  __syncthreads();
  if (t < 128) cnt[t] = off[t] - v;          // cursors
  __syncthreads();
  for (int i=s+t; i<e; i+=512){
    int u = pairs[i];
    int p = s + atomicAdd(&cnt[u & 127], 1);
    csr[p] = u >> 7;
  }
}

// ---------------- MFMA GEMM layer 0: hs = bf16( (x @ W) * dinv ), K=128 ----------------

__global__ __launch_bounds__(256) void k_gemm0m(const float* __restrict__ x,
    const float* __restrict__ W, const float* __restrict__ dinv,
    ushort_t* __restrict__ hs){
  __shared__ __attribute__((aligned(16))) ushort_t Wt[64*136];
  int t = threadIdx.x;
  for (int i=t; i<128*64; i+=256){
    int k = i>>6, n = i&63;
    Wt[n*136 + k] = f2bf(W[i]);
  }
  __syncthreads();
  int lane = t & 63, wv = t >> 6;
  int n0 = lane & 15, quad = lane >> 4;
  int r0 = blockIdx.x*64 + wv*16;
  int row = r0 + n0;
  int rowc = (row < NN)? row : NN-1;
  const float* xr = x + (size_t)rowc*128 + quad*8;
  floatx4 acc[4] = {{0,0,0,0},{0,0,0,0},{0,0,0,0},{0,0,0,0}};
  #pragma unroll
  for (int ks=0; ks<4; ++ks){
    float4 a01 = *(const float4*)(xr + ks*32);
    float4 a23 = *(const float4*)(xr + ks*32 + 4);
    short8 af;
    af[0]=(short)f2bf(a01.x); af[1]=(short)f2bf(a01.y);
    af[2]=(short)f2bf(a01.z); af[3]=(short)f2bf(a01.w);
    af[4]=(short)f2bf(a23.x); af[5]=(short)f2bf(a23.y);
    af[6]=(short)f2bf(a23.z); af[7]=(short)f2bf(a23.w);
    #pragma unroll
    for (int tl=0; tl<4; ++tl){
      short8 bf = *(const short8*)(&Wt[(tl*16+n0)*136 + ks*32 + quad*8]);
      acc[tl] = __builtin_amdgcn_mfma_f32_16x16x32_bf16(af, bf, acc[tl], 0, 0, 0);
    }
  }
  #pragma unroll
  for (int reg=0; reg<4; ++reg){
    int rr = r0 + quad*4 + reg;
    if (rr < NN){
      float dv = dinv[rr];
      #pragma unroll
      for (int tl=0; tl<4; ++tl)
        hs[(size_t)rr*64 + tl*16 + n0] = f2bf(acc[tl][reg]*dv);
    }
  }
}

// ---------------- MFMA GEMM layers 1/2 with fused BN+ReLU on A, K=64 ----------------

__global__ __launch_bounds__(256) void k_gemmSm(const float* __restrict__ h,
    const float* __restrict__ W, const float* __restrict__ coeff,
    const float* __restrict__ dinv, ushort_t* __restrict__ hs){
  __shared__ __attribute__((aligned(16))) ushort_t Wt[64*72];
  int t = threadIdx.x;
  for (int i=t; i<64*64; i+=256){
    int k = i>>6, n = i&63;
    Wt[n*72 + k] = f2bf(W[i]);
  }
  __syncthreads();
  int lane = t & 63, wv = t >> 6;
  int n0 = lane & 15, quad = lane >> 4;
  int r0 = blockIdx.x*64 + wv*16;
  int row = r0 + n0;
  int rowc = (row < NN)? row : NN-1;
  const float* hr = h + (size_t)rowc*64 + quad*8;
  floatx4 acc[4] = {{0,0,0,0},{0,0,0,0},{0,0,0,0},{0,0,0,0}};
  #pragma unroll
  for (int ks=0; ks<2; ++ks){
    float4 a01 = *(const float4*)(hr + ks*32);
    float4 a23 = *(const float4*)(hr + ks*32 + 4);
    const float* cA = coeff + ks*32 + quad*8;
    float4 ca0 = *(const float4*)(cA),      ca1 = *(const float4*)(cA+4);
    float4 cb0 = *(const float4*)(cA+64),   cb1 = *(const float4*)(cA+68);
    short8 af;
    af[0]=(short)f2bf(fmaxf(fmaf(a01.x,ca0.x,cb0.x),0.f));
    af[1]=(short)f2bf(fmaxf(fmaf(a01.y,ca0.y,cb0.y),0.f));
    af[2]=(short)f2bf(fmaxf(fmaf(a01.z,ca0.z,cb0.z),0.f));
    af[3]=(short)f2bf(fmaxf(fmaf(a01.w,ca0.w,cb0.w),0.f));
    af[4]=(short)f2bf(fmaxf(fmaf(a23.x,ca1.x,cb1.x),0.f));
    af[5]=(short)f2bf(fmaxf(fmaf(a23.y,ca1.y,cb1.y),0.f));
    af[6]=(short)f2bf(fmaxf(fmaf(a23.z,ca1.z,cb1.z),0.f));
    af[7]=(short)f2bf(fmaxf(fmaf(a23.w,ca1.w,cb1.w),0.f));
    #pragma unroll
    for (int tl=0; tl<4; ++tl){
      short8 bf = *(const short8*)(&Wt[(tl*16+n0)*72 + ks*32 + quad*8]);
      acc[tl] = __builtin_amdgcn_mfma_f32_16x16x32_bf16(af, bf, acc[tl], 0, 0, 0);
    }
  }
  #pragma unroll
  for (int reg=0; reg<4; ++reg){
    int rr = r0 + quad*4 + reg;
    if (rr < NN){
      float dv = dinv[rr];
      #pragma unroll
      for (int tl=0; tl<4; ++tl)
        hs[(size_t)rr*64 + tl*16 + n0] = f2bf(acc[tl][reg]*dv);
    }
  }
}

// ---------------- pull-aggregation + fused BN-coeff (last-block reduction) ----------------

__global__ __launch_bounds__(256) void k_aggregate(const ushort_t* __restrict__ hs,
    const int* __restrict__ colptr, const int* __restrict__ csr,
    const float* __restrict__ dinv, const float* __restrict__ bias,
    float* __restrict__ out, float* __restrict__ stats,
    const float* __restrict__ g, const float* __restrict__ be,
    float* __restrict__ coeff, int* __restrict__ ticket){
  int t = threadIdx.x; int c = t & 63;
  int wv = blockIdx.x*4 + (t>>6);            // 8192 waves
  float bc = bias[c];
  float s1 = 0.f, s2 = 0.f;
  for (int v = wv; v < NN; v += 8192){
    int vv = __builtin_amdgcn_readfirstlane(v);
    int e0 = colptr[vv], e1 = colptr[vv+1];
    float acc = bf2f(hs[(size_t)vv*64 + c]);
    int e = e0;
    for (; e+8 <= e1; e += 8){
      int i0=csr[e],   i1=csr[e+1], i2=csr[e+2], i3=csr[e+3];
      int i4=csr[e+4], i5=csr[e+5], i6=csr[e+6], i7=csr[e+7];
      float f0=bf2f(hs[(size_t)i0*64+c]), f1=bf2f(hs[(size_t)i1*64+c]);
      float f2=bf2f(hs[(size_t)i2*64+c]), f3=bf2f(hs[(size_t)i3*64+c]);
      float f4=bf2f(hs[(size_t)i4*64+c]), f5=bf2f(hs[(size_t)i5*64+c]);
      float f6=bf2f(hs[(size_t)i6*64+c]), f7=bf2f(hs[(size_t)i7*64+c]);
      acc += ((f0+f1)+(f2+f3)) + ((f4+f5)+(f6+f7));
    }
    for (; e+4 <= e1; e += 4){
      int i0=csr[e], i1=csr[e+1], i2=csr[e+2], i3=csr[e+3];
      float f0=bf2f(hs[(size_t)i0*64+c]), f1=bf2f(hs[(size_t)i1*64+c]);
      float f2=bf2f(hs[(size_t)i2*64+c]), f3=bf2f(hs[(size_t)i3*64+c]);
      acc += (f0+f1)+(f2+f3);
    }
    for (; e<e1; ++e) acc += bf2f(hs[(size_t)csr[e]*64+c]);
    float o = acc*dinv[vv] + bc;
    out[(size_t)vv*64+c] = o;
    s1 += o; s2 += o*o;
  }
  __shared__ float l1[256], l2[256];
  __shared__ int amLast;
  l1[t]=s1; l2[t]=s2; __syncthreads();
  if (t < 64){
    float a1 = l1[t]+l1[t+64]+l1[t+128]+l1[t+192];
    float a2 = l2[t]+l2[t+64]+l2[t+128]+l2[t+192];
    float* rep = stats + (size_t)(blockIdx.x & 31)*128;
    atomicAdd(&rep[t],    a1);
    atomicAdd(&rep[64+t], a2);
  }
  __threadfence();
  if (t == 0) amLast = (atomicAdd(ticket, 1) == 2047);
  __syncthreads();
  if (amLast && t < 64){
    float u1=0.f, u2=0.f;
    for (int r=0;r<32;++r){
      u1 += __hip_atomic_load(&stats[r*128+t],    __ATOMIC_RELAXED, __HIP_MEMORY_SCOPE_AGENT);
      u2 += __hip_atomic_load(&stats[r*128+64+t], __ATOMIC_RELAXED, __HIP_MEMORY_SCOPE_AGENT);
    }
    float mu  = u1/(float)NN;
    float var = u2/(float)NN - mu*mu;
    float a   = g[t]*rsqrtf(var + 1e-5f);
    coeff[t]    = a;
    coeff[64+t] = be[t] - mu*a;
  }
}

// ---------------- pooling (BN+ReLU + graph-bounds search fused) ----------------

__global__ __launch_bounds__(256) void k_pool(const float* __restrict__ h, const int* __restrict__ batch,
                                              const float* __restrict__ cf, float* __restrict__ pooled){
  int t=threadIdx.x; int c=t&63;
  int g = __builtin_amdgcn_readfirstlane((int)(blockIdx.x*4 + (t>>6)));
  int lo=0, hi=NN;
  while (lo<hi){ int mid=(lo+hi)>>1; if (batch[mid]<g) lo=mid+1; else hi=mid; }
  int s = lo;
  hi = NN;
  while (lo<hi){ int mid=(lo+hi)>>1; if (batch[mid]<g+1) lo=mid+1; else hi=mid; }
  int e = lo;
  float a = cf[c], d = cf[64+c];
  float acc=0.f;
  for (int v=s; v<e; ++v) acc += fmaxf(fmaf(h[(size_t)v*64+c], a, d), 0.f);
  float inv = 1.0f / fmaxf((float)(e-s), 1.0f);
  pooled[(size_t)g*64+c] = acc*inv;
}

// ---------------- head: t = pooled@W1+b1, stats + last-block gcoeff ----------------

__global__ __launch_bounds__(256) void k_tkern(float* __restrict__ pooled, const float* __restrict__ W1,
                                               const float* __restrict__ b1, float* __restrict__ stats,
                                               const float* __restrict__ gf, const float* __restrict__ bf_,
                                               float* __restrict__ gcoeff, int* __restrict__ ticket){
  int t=threadIdx.x; int c=t&63;
  int g = __builtin_amdgcn_readfirstlane((int)(blockIdx.x*4 + (t>>6)));
  const float* p = pooled + (size_t)g*64;
  float acc = b1[c];
  #pragma unroll 4
  for (int k=0;k<64;++k) acc = fmaf(p[k], W1[k*64+c], acc);
  pooled[(size_t)g*64+c] = acc;
  float* rep = stats + (size_t)(blockIdx.x & 31)*128;
  atomicAdd(&rep[c],    acc);
  atomicAdd(&rep[64+c], acc*acc);
  __shared__ int amLast;
  __threadfence();
  if (t == 0) amLast = (atomicAdd(ticket, 1) == 1023);
  __syncthreads();
  if (amLast && t < 64){
    float u1=0.f, u2=0.f;
    for (int r=0;r<32;++r){
      u1 += __hip_atomic_load(&stats[r*128+t],    __ATOMIC_RELAXED, __HIP_MEMORY_SCOPE_AGENT);
      u2 += __hip_atomic_load(&stats[r*128+64+t], __ATOMIC_RELAXED, __HIP_MEMORY_SCOPE_AGENT);
    }
    float mu  = u1/(float)NG;
    float var = u2/(float)NG - mu*mu;
    float a   = gf[t]*rsqrtf(var + 1e-5f);
    gcoeff[t]    = a;
    gcoeff[64+t] = bf_[t] - mu*a;
  }
}

__global__ __launch_bounds__(256) void k_final(const float* __restrict__ tbuf, const float* __restrict__ gcf,
                                               const float* __restrict__ W2, const float* __restrict__ b2,
                                               float* __restrict__ out){
  int t=threadIdx.x; int c=t&63;
  int g = blockIdx.x*4 + (t>>6);
  float tv = tbuf[(size_t)g*64+c];
  float z  = fmaxf(fmaf(tv, gcf[c], gcf[64+c]), 0.f);
  float p  = z * W2[c];
  #pragma unroll
  for (int o=32;o>0;o>>=1) p += __shfl_xor(p, o, 64);
  if (c==0) out[g] = p + b2[0];
}

// ---------------- launch ----------------

extern "C" void kernel_launch(void* const* d_in, const int* in_sizes, int n_in,
                              void* d_out, int out_size, void* d_ws, size_t ws_size,
                              hipStream_t stream) {
  const float* x    = (const float*)d_in[0];
  const int*   ei   = (const int*)d_in[1];
  const int*   batch= (const int*)d_in[2];
  const float* Wc0=(const float*)d_in[3],  *bc0=(const float*)d_in[4];
  const float* g0 =(const float*)d_in[5],  *be0=(const float*)d_in[6];
  const float* Wc1=(const float*)d_in[7],  *bc1=(const float*)d_in[8];
  const float* g1 =(const float*)d_in[9],  *be1=(const float*)d_in[10];
  const float* Wc2=(const float*)d_in[11], *bc2=(const float*)d_in[12];
  const float* g2 =(const float*)d_in[13], *be2=(const float*)d_in[14];
  const float* W1 =(const float*)d_in[15], *b1 =(const float*)d_in[16];
  const float* gf =(const float*)d_in[17], *bf_=(const float*)d_in[18];
  const float* W2 =(const float*)d_in[19], *b2 =(const float*)d_in[20];
  float* out = (float*)d_out;

  char* w = (char*)d_ws;
  float*    stats  = (float*)   (w + 0);          // 4 sets x 32 reps x 128 f [zeroed by k_hist]
  int*      ticket = (int*)     (w + 65536);      // 4 ints [zeroed by k_hist]
  int*      total  = (int*)     (w + 65568);      // NBK
  int*      base   = (int*)     (w + 68704);      // NBK+1
  int*      colptr = (int*)     (w + 71840);      // NN+1
  float*    dinv   = (float*)   (w + 471856);
  float*    coeff  = (float*)   (w + 871856);
  float*    gcoeff = (float*)   (w + 872368);
  float*    pooled = (float*)   (w + 872880);     // NG x 64
  int*      csr    = (int*)     (w + 1921456);    // NE ints
  ushort_t* bufA   = (ushort_t*)(w + 14721456);   // hs bf16 row-major
  float*    bufB   = (float*)   (w + 27521456);   // h fp32 row-major (pre-BN); ends ~53.1 MB
  int*      histT  = csr;                         // alias: dead before k_fine writes csr (NBKxNB = 1.6 MB)
  int*      pairs  = (int*)bufB;                  // alias: dead before bufB first write

  // CSR build (no global atomics); k_hist also zeroes stats+tickets
  k_hist <<<NB,  512,  0, stream>>>(ei, histT, (float4*)w);
  k_scanA<<<196, 256,  0, stream>>>(histT, total);
  k_scanB<<<1,   1024, 0, stream>>>(total, base);
  k_pairs<<<NB,  512,  0, stream>>>(ei, histT, base, pairs);
  k_fine <<<NBK, 512,  0, stream>>>(pairs, base, csr, colptr, dinv);

  // layer 0
  k_gemm0m<<<1563, 256, 0, stream>>>(x, Wc0, dinv, bufA);
  k_aggregate<<<2048, 256, 0, stream>>>(bufA, colptr, csr, dinv, bc0, bufB, stats + 0*4096,
                                        g0, be0, coeff, ticket + 0);
  // layer 1 (BN+ReLU of layer 0 fused into A-path)
  k_gemmSm<<<1563, 256, 0, stream>>>(bufB, Wc1, coeff, dinv, bufA);
  k_aggregate<<<2048, 256, 0, stream>>>(bufA, colptr, csr, dinv, bc1, bufB, stats + 1*4096,
                                        g1, be1, coeff, ticket + 1);
  // layer 2
  k_gemmSm<<<1563, 256, 0, stream>>>(bufB, Wc2, coeff, dinv, bufA);
  k_aggregate<<<2048, 256, 0, stream>>>(bufA, colptr, csr, dinv, bc2, bufB, stats + 2*4096,
                                        g2, be2, coeff, ticket + 2);

  // head (BN+ReLU of layer 2 fused into pool; gbounds fused as per-wave search)
  k_pool <<<NG/4, 256, 0, stream>>>(bufB, batch, coeff, pooled);
  k_tkern<<<NG/4, 256, 0, stream>>>(pooled, W1, b1, stats + 3*4096, gf, bf_, gcoeff, ticket + 3);
  k_final<<<NG/4, 256, 0, stream>>>(pooled, gcoeff, W2, b2, out);
}

// Round 11
// 545.509 us; speedup vs baseline: 2.3741x; 2.3741x over previous
//
#include <hip/hip_runtime.h>
#include <hip/hip_bf16.h>

#define NN 100000
#define NE 3200000
#define NG 4096
#define NB 256          // blocks in hist/pairs; NE/NB = 12500 exactly
#define NBK 782         // coarse buckets of 128 nodes

typedef unsigned short ushort_t;
typedef short short8 __attribute__((ext_vector_type(8)));
typedef float floatx4 __attribute__((ext_vector_type(4)));

__device__ __forceinline__ float bf2f(unsigned short u){
  union{unsigned int i; float f;} x; x.i = ((unsigned)u)<<16; return x.f;
}
__device__ __forceinline__ ushort_t f2bf(float f){
  union{float f; unsigned int i;} x; x.f = f;
  unsigned int r = x.i + 0x7fff + ((x.i >> 16) & 1);
  return (ushort_t)(r >> 16);
}

// ---------------- CSR build: hierarchical counting sort ----------------

__global__ __launch_bounds__(512) void k_hist(const int* __restrict__ ei, int* __restrict__ histT){
  __shared__ int lh[NBK];
  int b = blockIdx.x, t = threadIdx.x;
  for (int k=t; k<NBK; k+=512) lh[k]=0;
  __syncthreads();
  int e0 = b*(NE/NB);
  for (int e=e0+t; e<e0+(NE/NB); e+=512) atomicAdd(&lh[ei[NE+e]>>7], 1);
  __syncthreads();
  for (int k=t; k<NBK; k+=512) histT[(size_t)k*NB+b] = lh[k];
}

__global__ __launch_bounds__(256) void k_scanA(int* __restrict__ histT, int* __restrict__ total){
  int wv = blockIdx.x*4 + (threadIdx.x>>6);
  int lane = threadIdx.x & 63;
  if (wv >= NBK) return;
  int* row = histT + (size_t)wv*NB;
  int carry = 0;
  #pragma unroll
  for (int ch=0; ch<NB/64; ++ch){
    int a = row[ch*64+lane];
    int inc = a;
    for (int off=1; off<64; off<<=1){
      int x = __shfl_up(inc, off, 64);
      if (lane >= off) inc += x;
    }
    row[ch*64+lane] = carry + inc - a;       // exclusive
    carry += __shfl(inc, 63, 64);
  }
  if (lane==0) total[wv] = carry;
}

__global__ void k_scanB(const int* __restrict__ total, int* __restrict__ base){
  __shared__ int lds[1024];
  int t = threadIdx.x;
  int v = (t < NBK)? total[t] : 0;
  lds[t] = v; __syncthreads();
  for (int off=1; off<1024; off<<=1){
    int x = (t>=off)? lds[t-off] : 0;
    __syncthreads();
    lds[t] += x;
    __syncthreads();
  }
  if (t < NBK)      base[t]   = lds[t]-v;
  if (t == NBK-1)   base[NBK] = lds[t];      // == NE
}

__global__ __launch_bounds__(512) void k_pairs(const int* __restrict__ ei,
    const int* __restrict__ histT, const int* __restrict__ base,
    int* __restrict__ pairs){
  __shared__ int cur[NBK];
  int b = blockIdx.x, t = threadIdx.x;
  for (int k=t; k<NBK; k+=512) cur[k] = base[k] + histT[(size_t)k*NB + b];
  __syncthreads();
  int e0 = b*(NE/NB);
  for (int e=e0+t; e<e0+(NE/NB); e+=512){
    int src = ei[e], dst = ei[NE+e];
    int p = atomicAdd(&cur[dst>>7], 1);      // LDS atomic
    pairs[p] = (src << 7) | (dst & 127);
  }
}

// per-bucket 7-bit counting sort -> csr; colptr, dinv
__global__ __launch_bounds__(256) void k_fine(const int* __restrict__ pairs,
    const int* __restrict__ base, int* __restrict__ csr,
    int* __restrict__ colptr, float* __restrict__ dinv){
  __shared__ int cnt[128], off[128];
  int k = blockIdx.x, t = threadIdx.x;
  if (t < 128) cnt[t] = 0;
  __syncthreads();
  int s = base[k], e = base[k+1];
  for (int i=s+t; i<e; i+=256) atomicAdd(&cnt[pairs[i] & 127], 1);
  __syncthreads();
  int v = (t<128)? cnt[t] : 0;
  if (t<128) off[t] = v;
  __syncthreads();
  for (int o=1; o<128; o<<=1){
    int x = (t>=o && t<128)? off[t-o] : 0;
    __syncthreads();
    if (t<128) off[t] += x;
    __syncthreads();
  }
  int node0 = k*128;
  if (t < 128 && node0+t < NN){
    colptr[node0+t] = s + off[t] - v;
    dinv[node0+t]   = rsqrtf((float)cnt[t] + 1.0f);
  }
  if (k == NBK-1 && t == 0) colptr[NN] = NE;
  __syncthreads();
  if (t < 128) cnt[t] = off[t] - v;          // cursors
  __syncthreads();
  for (int i=s+t; i<e; i+=256){
    int u = pairs[i];
    int p = s + atomicAdd(&cnt[u & 127], 1);
    csr[p] = u >> 7;
  }
}

// ---------------- MFMA GEMM layer 0: hs = bf16( (x @ W) * dinv ), K=128 ----------------

__global__ __launch_bounds__(256) void k_gemm0m(const float* __restrict__ x,
    const float* __restrict__ W, const float* __restrict__ dinv,
    ushort_t* __restrict__ hs){
  __shared__ __attribute__((aligned(16))) ushort_t Wt[64*136];
  int t = threadIdx.x;
  for (int i=t; i<128*64; i+=256){
    int k = i>>6, n = i&63;
    Wt[n*136 + k] = f2bf(W[i]);
  }
  __syncthreads();
  int lane = t & 63, wv = t >> 6;
  int n0 = lane & 15, quad = lane >> 4;
  int r0 = blockIdx.x*64 + wv*16;
  int row = r0 + n0;
  int rowc = (row < NN)? row : NN-1;
  const float* xr = x + (size_t)rowc*128 + quad*8;
  floatx4 acc[4] = {{0,0,0,0},{0,0,0,0},{0,0,0,0},{0,0,0,0}};
  #pragma unroll
  for (int ks=0; ks<4; ++ks){
    float4 a01 = *(const float4*)(xr + ks*32);
    float4 a23 = *(const float4*)(xr + ks*32 + 4);
    short8 af;
    af[0]=(short)f2bf(a01.x); af[1]=(short)f2bf(a01.y);
    af[2]=(short)f2bf(a01.z); af[3]=(short)f2bf(a01.w);
    af[4]=(short)f2bf(a23.x); af[5]=(short)f2bf(a23.y);
    af[6]=(short)f2bf(a23.z); af[7]=(short)f2bf(a23.w);
    #pragma unroll
    for (int tl=0; tl<4; ++tl){
      short8 bf = *(const short8*)(&Wt[(tl*16+n0)*136 + ks*32 + quad*8]);
      acc[tl] = __builtin_amdgcn_mfma_f32_16x16x32_bf16(af, bf, acc[tl], 0, 0, 0);
    }
  }
  #pragma unroll
  for (int reg=0; reg<4; ++reg){
    int rr = r0 + quad*4 + reg;
    if (rr < NN){
      float dv = dinv[rr];
      #pragma unroll
      for (int tl=0; tl<4; ++tl)
        hs[(size_t)rr*64 + tl*16 + n0] = f2bf(acc[tl][reg]*dv);
    }
  }
}

// ---------------- MFMA GEMM layers 1/2 with fused BN+ReLU on A, K=64 ----------------

__global__ __launch_bounds__(256) void k_gemmSm(const float* __restrict__ h,
    const float* __restrict__ W, const float* __restrict__ coeff,
    const float* __restrict__ dinv, ushort_t* __restrict__ hs){
  __shared__ __attribute__((aligned(16))) ushort_t Wt[64*72];
  int t = threadIdx.x;
  for (int i=t; i<64*64; i+=256){
    int k = i>>6, n = i&63;
    Wt[n*72 + k] = f2bf(W[i]);
  }
  __syncthreads();
  int lane = t & 63, wv = t >> 6;
  int n0 = lane & 15, quad = lane >> 4;
  int r0 = blockIdx.x*64 + wv*16;
  int row = r0 + n0;
  int rowc = (row < NN)? row : NN-1;
  const float* hr = h + (size_t)rowc*64 + quad*8;
  floatx4 acc[4] = {{0,0,0,0},{0,0,0,0},{0,0,0,0},{0,0,0,0}};
  #pragma unroll
  for (int ks=0; ks<2; ++ks){
    float4 a01 = *(const float4*)(hr + ks*32);
    float4 a23 = *(const float4*)(hr + ks*32 + 4);
    const float* cA = coeff + ks*32 + quad*8;
    float4 ca0 = *(const float4*)(cA),      ca1 = *(const float4*)(cA+4);
    float4 cb0 = *(const float4*)(cA+64),   cb1 = *(const float4*)(cA+68);
    short8 af;
    af[0]=(short)f2bf(fmaxf(fmaf(a01.x,ca0.x,cb0.x),0.f));
    af[1]=(short)f2bf(fmaxf(fmaf(a01.y,ca0.y,cb0.y),0.f));
    af[2]=(short)f2bf(fmaxf(fmaf(a01.z,ca0.z,cb0.z),0.f));
    af[3]=(short)f2bf(fmaxf(fmaf(a01.w,ca0.w,cb0.w),0.f));
    af[4]=(short)f2bf(fmaxf(fmaf(a23.x,ca1.x,cb1.x),0.f));
    af[5]=(short)f2bf(fmaxf(fmaf(a23.y,ca1.y,cb1.y),0.f));
    af[6]=(short)f2bf(fmaxf(fmaf(a23.z,ca1.z,cb1.z),0.f));
    af[7]=(short)f2bf(fmaxf(fmaf(a23.w,ca1.w,cb1.w),0.f));
    #pragma unroll
    for (int tl=0; tl<4; ++tl){
      short8 bf = *(const short8*)(&Wt[(tl*16+n0)*72 + ks*32 + quad*8]);
      acc[tl] = __builtin_amdgcn_mfma_f32_16x16x32_bf16(af, bf, acc[tl], 0, 0, 0);
    }
  }
  #pragma unroll
  for (int reg=0; reg<4; ++reg){
    int rr = r0 + quad*4 + reg;
    if (rr < NN){
      float dv = dinv[rr];
      #pragma unroll
      for (int tl=0; tl<4; ++tl)
        hs[(size_t)rr*64 + tl*16 + n0] = f2bf(acc[tl][reg]*dv);
    }
  }
}

// ---------------- pull-aggregation (r9 form) + non-temporal out stores ----------------

__global__ __launch_bounds__(256) void k_aggregate(const ushort_t* __restrict__ hs,
    const int* __restrict__ colptr, const int* __restrict__ csr,
    const float* __restrict__ dinv, const float* __restrict__ bias,
    float* __restrict__ out, float* __restrict__ stats){
  int t = threadIdx.x; int c = t & 63;
  int wv = blockIdx.x*4 + (t>>6);            // 8192 waves
  float bc = bias[c];
  float s1 = 0.f, s2 = 0.f;
  for (int v = wv; v < NN; v += 8192){
    int vv = __builtin_amdgcn_readfirstlane(v);
    int e0 = colptr[vv], e1 = colptr[vv+1];
    float acc = bf2f(hs[(size_t)vv*64 + c]);
    int e = e0;
    for (; e+8 <= e1; e += 8){
      int i0=csr[e],   i1=csr[e+1], i2=csr[e+2], i3=csr[e+3];
      int i4=csr[e+4], i5=csr[e+5], i6=csr[e+6], i7=csr[e+7];
      float f0=bf2f(hs[(size_t)i0*64+c]), f1=bf2f(hs[(size_t)i1*64+c]);
      float f2=bf2f(hs[(size_t)i2*64+c]), f3=bf2f(hs[(size_t)i3*64+c]);
      float f4=bf2f(hs[(size_t)i4*64+c]), f5=bf2f(hs[(size_t)i5*64+c]);
      float f6=bf2f(hs[(size_t)i6*64+c]), f7=bf2f(hs[(size_t)i7*64+c]);
      acc += ((f0+f1)+(f2+f3)) + ((f4+f5)+(f6+f7));
    }
    for (; e+4 <= e1; e += 4){
      int i0=csr[e], i1=csr[e+1], i2=csr[e+2], i3=csr[e+3];
      float f0=bf2f(hs[(size_t)i0*64+c]), f1=bf2f(hs[(size_t)i1*64+c]);
      float f2=bf2f(hs[(size_t)i2*64+c]), f3=bf2f(hs[(size_t)i3*64+c]);
      acc += (f0+f1)+(f2+f3);
    }
    for (; e<e1; ++e) acc += bf2f(hs[(size_t)csr[e]*64+c]);
    float o = acc*dinv[vv] + bc;
    __builtin_nontemporal_store(o, &out[(size_t)vv*64+c]);   // keep L2 for hs
    s1 += o; s2 += o*o;
  }
  __shared__ float l1[256], l2[256];
  l1[t]=s1; l2[t]=s2; __syncthreads();
  if (t < 64){
    float a1 = l1[t]+l1[t+64]+l1[t+128]+l1[t+192];
    float a2 = l2[t]+l2[t+64]+l2[t+128]+l2[t+192];
    float* rep = stats + (size_t)(blockIdx.x & 31)*128;
    atomicAdd(&rep[t],    a1);
    atomicAdd(&rep[64+t], a2);
  }
}

// ---------------- BN coeff ----------------

__global__ void k_bncoeff(const float* __restrict__ stats, const float* __restrict__ g,
                          const float* __restrict__ be, float cnt, float* __restrict__ coeff){
  int c = threadIdx.x;                       // 64
  float s1=0.f, s2=0.f;
  for (int r=0;r<32;++r){ s1 += stats[r*128+c]; s2 += stats[r*128+64+c]; }
  float mu  = s1/cnt;
  float var = s2/cnt - mu*mu;
  float a   = g[c]*rsqrtf(var + 1e-5f);
  coeff[c]    = a;
  coeff[64+c] = be[c] - mu*a;
}

// ---------------- fused pool (bounds search + BN+ReLU + mean) + W1 matmul + stats ----------------

__global__ __launch_bounds__(256) void k_poolhead(const float* __restrict__ h,
    const int* __restrict__ batch, const float* __restrict__ cf,
    const float* __restrict__ W1, const float* __restrict__ b1,
    float* __restrict__ tbuf, float* __restrict__ stats){
  __shared__ float pl[256];
  int t=threadIdx.x; int c=t&63; int wv=t>>6;
  int g = __builtin_amdgcn_readfirstlane((int)(blockIdx.x*4 + wv));
  int lo=0, hi=NN;
  while (lo<hi){ int mid=(lo+hi)>>1; if (batch[mid]<g) lo=mid+1; else hi=mid; }
  int s = lo;
  hi = NN;
  while (lo<hi){ int mid=(lo+hi)>>1; if (batch[mid]<g+1) lo=mid+1; else hi=mid; }
  int e = lo;
  float a = cf[c], d = cf[64+c];
  float acc=0.f;
  for (int v=s; v<e; ++v) acc += fmaxf(fmaf(h[(size_t)v*64+c], a, d), 0.f);
  float inv = 1.0f / fmaxf((float)(e-s), 1.0f);
  pl[wv*64 + c] = acc*inv;
  __syncthreads();
  const float* p = pl + wv*64;
  float tk = b1[c];
  #pragma unroll 4
  for (int k=0;k<64;++k) tk = fmaf(p[k], W1[k*64+c], tk);
  tbuf[(size_t)g*64+c] = tk;
  float* rep = stats + (size_t)(blockIdx.x & 31)*128;
  atomicAdd(&rep[c],    tk);
  atomicAdd(&rep[64+c], tk*tk);
}

__global__ __launch_bounds__(256) void k_final(const float* __restrict__ tbuf, const float* __restrict__ gcf,
                                               const float* __restrict__ W2, const float* __restrict__ b2,
                                               float* __restrict__ out){
  int t=threadIdx.x; int c=t&63;
  int g = blockIdx.x*4 + (t>>6);
  float tv = tbuf[(size_t)g*64+c];
  float z  = fmaxf(fmaf(tv, gcf[c], gcf[64+c]), 0.f);
  float p  = z * W2[c];
  #pragma unroll
  for (int o=32;o>0;o>>=1) p += __shfl_xor(p, o, 64);
  if (c==0) out[g] = p + b2[0];
}

// ---------------- launch ----------------

extern "C" void kernel_launch(void* const* d_in, const int* in_sizes, int n_in,
                              void* d_out, int out_size, void* d_ws, size_t ws_size,
                              hipStream_t stream) {
  const float* x    = (const float*)d_in[0];
  const int*   ei   = (const int*)d_in[1];
  const int*   batch= (const int*)d_in[2];
  const float* Wc0=(const float*)d_in[3],  *bc0=(const float*)d_in[4];
  const float* g0 =(const float*)d_in[5],  *be0=(const float*)d_in[6];
  const float* Wc1=(const float*)d_in[7],  *bc1=(const float*)d_in[8];
  const float* g1 =(const float*)d_in[9],  *be1=(const float*)d_in[10];
  const float* Wc2=(const float*)d_in[11], *bc2=(const float*)d_in[12];
  const float* g2 =(const float*)d_in[13], *be2=(const float*)d_in[14];
  const float* W1 =(const float*)d_in[15], *b1 =(const float*)d_in[16];
  const float* gf =(const float*)d_in[17], *bf_=(const float*)d_in[18];
  const float* W2 =(const float*)d_in[19], *b2 =(const float*)d_in[20];
  float* out = (float*)d_out;

  char* w = (char*)d_ws;
  float*    stats  = (float*)   (w + 0);          // 4 sets x 32 reps x 128 f [zeroed]
  int*      total  = (int*)     (w + 65536);      // NBK
  int*      base   = (int*)     (w + 68736);      // NBK+1
  int*      colptr = (int*)     (w + 71936);      // NN+1
  float*    dinv   = (float*)   (w + 471952);
  float*    coeff  = (float*)   (w + 871952);
  float*    gcoeff = (float*)   (w + 872464);
  float*    pooled = (float*)   (w + 872976);     // NG x 64
  int*      csr    = (int*)     (w + 1921552);    // NE ints
  ushort_t* bufA   = (ushort_t*)(w + 14721552);   // hs bf16 row-major
  float*    bufB   = (float*)   (w + 27521552);   // h fp32 row-major (pre-BN); ends ~53.1 MB
  int*      histT  = csr;                         // alias: dead before k_fine writes csr
  int*      pairs  = (int*)bufB;                  // alias: dead before bufB first write

  hipMemsetAsync(stats, 0, 65536, stream);

  // CSR build (no global atomics)
  k_hist <<<NB,  512,  0, stream>>>(ei, histT);
  k_scanA<<<196, 256,  0, stream>>>(histT, total);
  k_scanB<<<1,   1024, 0, stream>>>(total, base);
  k_pairs<<<NB,  512,  0, stream>>>(ei, histT, base, pairs);
  k_fine <<<NBK, 256,  0, stream>>>(pairs, base, csr, colptr, dinv);

  // layer 0
  k_gemm0m<<<1563, 256, 0, stream>>>(x, Wc0, dinv, bufA);
  k_aggregate<<<2048, 256, 0, stream>>>(bufA, colptr, csr, dinv, bc0, bufB, stats + 0*4096);
  k_bncoeff<<<1, 64, 0, stream>>>(stats + 0*4096, g0, be0, (float)NN, coeff);
  // layer 1 (BN+ReLU of layer 0 fused into A-path)
  k_gemmSm<<<1563, 256, 0, stream>>>(bufB, Wc1, coeff, dinv, bufA);
  k_aggregate<<<2048, 256, 0, stream>>>(bufA, colptr, csr, dinv, bc1, bufB, stats + 1*4096);
  k_bncoeff<<<1, 64, 0, stream>>>(stats + 1*4096, g1, be1, (float)NN, coeff);
  // layer 2
  k_gemmSm<<<1563, 256, 0, stream>>>(bufB, Wc2, coeff, dinv, bufA);
  k_aggregate<<<2048, 256, 0, stream>>>(bufA, colptr, csr, dinv, bc2, bufB, stats + 2*4096);
  k_bncoeff<<<1, 64, 0, stream>>>(stats + 2*4096, g2, be2, (float)NN, coeff);

  // head (BN+ReLU of layer 2 + bounds search + mean + W1 fused)
  k_poolhead<<<NG/4, 256, 0, stream>>>(bufB, batch, coeff, W1, b1, pooled, stats + 3*4096);
  k_bncoeff<<<1, 64, 0, stream>>>(stats + 3*4096, gf, bf_, (float)NG, gcoeff);
  k_final<<<NG/4, 256, 0, stream>>>(pooled, gcoeff, W2, b2, out);
}